// Round 1
// baseline (1136.984 us; speedup 1.0000x reference)
//
#include <hip/hip_runtime.h>

#define NJ 7
#define HID 4

__device__ __forceinline__ float fsig(float v) {
    // 1 / (1 + e^-v) = 1 / (1 + 2^(-v*log2e))
    float e = __builtin_amdgcn_exp2f(v * -1.44269504f);
    return __builtin_amdgcn_rcpf(1.0f + e);
}
__device__ __forceinline__ float ftanh(float v) {
    // tanh(v) = 1 - 2/(e^{2v}+1);  e^{2v} = 2^{2v*log2e}
    // v large -> e=inf -> rcp=0 -> 1; v very negative -> e=0 -> 1-2 = -1. Safe.
    float e = __builtin_amdgcn_exp2f(v * 2.88539008f);
    return 1.0f - 2.0f * __builtin_amdgcn_rcpf(e + 1.0f);
}

__global__ __launch_bounds__(256) void aggreg_kernel(
    const float* __restrict__ x,
    const float* __restrict__ Wj,    const float* __restrict__ bj,
    const float* __restrict__ Wm,    const float* __restrict__ bm,
    const float* __restrict__ Wih_j, const float* __restrict__ Whh_j,
    const float* __restrict__ bih_j, const float* __restrict__ bhh_j,
    const float* __restrict__ Wih_m, const float* __restrict__ Whh_m,
    const float* __restrict__ bih_m, const float* __restrict__ bhh_m,
    const float* __restrict__ Wact,  const float* __restrict__ bact,
    float* __restrict__ out, int B)
{
    int row = blockIdx.x * blockDim.x + threadIdx.x;
    if (row >= B) return;

    const float* xp = x + (size_t)row * 19;
    float xr[19];
    #pragma unroll
    for (int i = 0; i < 19; ++i) xr[i] = xp[i];

    // h_j init: jcat (7,2) @ Wj.T (2->4) + bj.  j = xr[5..11], jd = xr[12..18]
    float hj[NJ][HID], hm[HID];
    #pragma unroll
    for (int t = 0; t < NJ; ++t) {
        #pragma unroll
        for (int o = 0; o < HID; ++o)
            hj[t][o] = bj[o] + Wj[o*2+0]*xr[5+t] + Wj[o*2+1]*xr[12+t];
    }
    // h_m init: obs (5) @ Wm.T (5->4) + bm
    #pragma unroll
    for (int o = 0; o < HID; ++o) {
        float a = bm[o];
        #pragma unroll
        for (int k = 0; k < 5; ++k) a += Wm[o*5+k]*xr[k];
        hm[o] = a;
    }

    // 7 message-passing iterations (outer loop NOT unrolled: keeps I-footprint small,
    // weight s_loads hit scalar cache each iter; no runtime-indexed arrays inside)
    for (int it = 0; it < 7; ++it) {
        // --- m-GRU: input = hj[0], hidden = hm ---
        float gim[12], ghm[12];
        #pragma unroll
        for (int g = 0; g < 12; ++g) {
            float a = bih_m[g], b = bhh_m[g];
            #pragma unroll
            for (int k = 0; k < HID; ++k) {
                a += Wih_m[g*4+k] * hj[0][k];
                b += Whh_m[g*4+k] * hm[k];
            }
            gim[g] = a; ghm[g] = b;
        }
        float hmn[HID];
        #pragma unroll
        for (int i = 0; i < HID; ++i) {
            float r = fsig(gim[i]   + ghm[i]);
            float z = fsig(gim[4+i] + ghm[4+i]);
            float n = ftanh(gim[8+i] + r * ghm[8+i]);
            hmn[i] = (1.0f - z) * n + z * hm[i];
        }

        // --- joint GRU: xin[t] = [left[t], right[t]], left[0]=hm (OLD), left[t]=hj[t-1],
        //     right[t]=hj[t+1] (t<6) else 0 ---
        float hjn[NJ][HID];
        #pragma unroll
        for (int t = 0; t < NJ; ++t) {
            float xin[8];
            #pragma unroll
            for (int k = 0; k < HID; ++k) {
                xin[k]     = (t == 0) ? hm[k]      : hj[t-1][k];
                xin[4 + k] = (t < 6) ? hj[t+1][k] : 0.0f;
            }
            float gi[12], gh[12];
            #pragma unroll
            for (int g = 0; g < 12; ++g) {
                float a = bih_j[g], b = bhh_j[g];
                #pragma unroll
                for (int k = 0; k < 8; ++k)   a += Wih_j[g*8+k] * xin[k];
                #pragma unroll
                for (int k = 0; k < HID; ++k) b += Whh_j[g*4+k] * hj[t][k];
                gi[g] = a; gh[g] = b;
            }
            #pragma unroll
            for (int i = 0; i < HID; ++i) {
                float r = fsig(gi[i]   + gh[i]);
                float z = fsig(gi[4+i] + gh[4+i]);
                float n = ftanh(gi[8+i] + r * gh[8+i]);
                hjn[t][i] = (1.0f - z) * n + z * hj[t][i];
            }
        }

        #pragma unroll
        for (int t = 0; t < NJ; ++t)
            #pragma unroll
            for (int i = 0; i < HID; ++i) hj[t][i] = hjn[t][i];
        #pragma unroll
        for (int i = 0; i < HID; ++i) hm[i] = hmn[i];
    }

    // acts = hj @ Wact.T + bact  -> (7,)
    float* op = out + (size_t)row * 7;
    #pragma unroll
    for (int t = 0; t < NJ; ++t) {
        float a = bact[0];
        #pragma unroll
        for (int k = 0; k < HID; ++k) a += Wact[k] * hj[t][k];
        op[t] = a;
    }
}

extern "C" void kernel_launch(void* const* d_in, const int* in_sizes, int n_in,
                              void* d_out, int out_size, void* d_ws, size_t ws_size,
                              hipStream_t stream) {
    const float* x      = (const float*)d_in[0];
    const float* Wj     = (const float*)d_in[1];
    const float* bj     = (const float*)d_in[2];
    const float* Wm     = (const float*)d_in[3];
    const float* bm     = (const float*)d_in[4];
    const float* Wih_j  = (const float*)d_in[5];
    const float* Whh_j  = (const float*)d_in[6];
    const float* bih_j  = (const float*)d_in[7];
    const float* bhh_j  = (const float*)d_in[8];
    const float* Wih_m  = (const float*)d_in[9];
    const float* Whh_m  = (const float*)d_in[10];
    const float* bih_m  = (const float*)d_in[11];
    const float* bhh_m  = (const float*)d_in[12];
    const float* Wact   = (const float*)d_in[13];
    const float* bact   = (const float*)d_in[14];
    float* out = (float*)d_out;

    int B = in_sizes[0] / 19;
    const int block = 256;
    const int grid  = (B + block - 1) / block;
    aggreg_kernel<<<grid, block, 0, stream>>>(
        x, Wj, bj, Wm, bm, Wih_j, Whh_j, bih_j, bhh_j,
        Wih_m, Whh_m, bih_m, bhh_m, Wact, bact, out, B);
}

// Round 3
// 526.638 us; speedup vs baseline: 2.1590x; 2.1590x over previous
//
#include <hip/hip_runtime.h>

typedef __attribute__((ext_vector_type(2))) _Float16 half2_t;

#define NJ 7
#define HID 4

// ---- ws layout (u32 slots) ----
// [0..47]    WIHJ: 12 gates x 4 half2 (pre-scaled: g<8 by -log2e, g>=8 by 2*log2e)
// [48..71]   WHHJ: 12 gates x 2 half2 (same scaling)
// [72..95]   WIHM: 12 x 2 half2
// [96..119]  WHHM: 12 x 2 half2
// [120..127] BSUMJ rz: 8 f32   ((bih+bhh)*-log2e)
// [128..131] BIHJ_n: 4 f32     (*2log2e)
// [132..135] BHHJ_n: 4 f32     (*2log2e)
// [136..143] BSUMM rz: 8 f32
// [144..147] BIHM_n: 4 f32
// [148..151] BHHM_n: 4 f32

__device__ __forceinline__ half2_t h2(unsigned int u) {
    return __builtin_bit_cast(half2_t, u);
}
__device__ __forceinline__ float fdot2f(half2_t a, half2_t b, float c) {
#if __has_builtin(__builtin_amdgcn_fdot2)
    return __builtin_amdgcn_fdot2(a, b, c, false);
#else
    return c + (float)a.x * (float)b.x + (float)a.y * (float)b.y;
#endif
}
__device__ __forceinline__ half2_t pk(float a, float b) {
    return __builtin_bit_cast(half2_t, __builtin_amdgcn_cvt_pkrtz(a, b));
}

__global__ __launch_bounds__(256) void prep_kernel(
    const float* __restrict__ Wih_j, const float* __restrict__ Whh_j,
    const float* __restrict__ bih_j, const float* __restrict__ bhh_j,
    const float* __restrict__ Wih_m, const float* __restrict__ Whh_m,
    const float* __restrict__ bih_m, const float* __restrict__ bhh_m,
    unsigned int* __restrict__ ws)
{
    const float c1 = -1.44269504f;  // -log2(e): r,z gates
    const float c2 = 2.88539008f;   // 2*log2(e): n gates
    int t = threadIdx.x;
    if (t < 48) {                       // WIHJ
        int g = t >> 2, k = t & 3;
        float s = (g < 8) ? c1 : c2;
        ws[t] = __builtin_bit_cast(unsigned int,
                    pk(Wih_j[g*8 + 2*k] * s, Wih_j[g*8 + 2*k + 1] * s));
    } else if (t < 72) {                // WHHJ
        int i = t - 48; int g = i >> 1, k = i & 1;
        float s = (g < 8) ? c1 : c2;
        ws[t] = __builtin_bit_cast(unsigned int,
                    pk(Whh_j[g*4 + 2*k] * s, Whh_j[g*4 + 2*k + 1] * s));
    } else if (t < 96) {                // WIHM
        int i = t - 72; int g = i >> 1, k = i & 1;
        float s = (g < 8) ? c1 : c2;
        ws[t] = __builtin_bit_cast(unsigned int,
                    pk(Wih_m[g*4 + 2*k] * s, Wih_m[g*4 + 2*k + 1] * s));
    } else if (t < 120) {               // WHHM
        int i = t - 96; int g = i >> 1, k = i & 1;
        float s = (g < 8) ? c1 : c2;
        ws[t] = __builtin_bit_cast(unsigned int,
                    pk(Whh_m[g*4 + 2*k] * s, Whh_m[g*4 + 2*k + 1] * s));
    } else if (t < 128) {               // BSUMJ rz
        int g = t - 120;
        ws[t] = __float_as_uint((bih_j[g] + bhh_j[g]) * c1);
    } else if (t < 132) {               // BIHJ_n
        int i = t - 128;
        ws[t] = __float_as_uint(bih_j[8 + i] * c2);
    } else if (t < 136) {               // BHHJ_n
        int i = t - 132;
        ws[t] = __float_as_uint(bhh_j[8 + i] * c2);
    } else if (t < 144) {               // BSUMM rz
        int g = t - 136;
        ws[t] = __float_as_uint((bih_m[g] + bhh_m[g]) * c1);
    } else if (t < 148) {               // BIHM_n
        int i = t - 144;
        ws[t] = __float_as_uint(bih_m[8 + i] * c2);
    } else if (t < 152) {               // BHHM_n
        int i = t - 148;
        ws[t] = __float_as_uint(bhh_m[8 + i] * c2);
    }
}

__global__ __launch_bounds__(256) void aggreg_kernel(
    const float* __restrict__ x,
    const float* __restrict__ Wj,   const float* __restrict__ bj,
    const float* __restrict__ Wm,   const float* __restrict__ bm,
    const float* __restrict__ Wact, const float* __restrict__ bact,
    const unsigned int* __restrict__ wu,
    float* __restrict__ out, int B)
{
    int row = blockIdx.x * blockDim.x + threadIdx.x;
    if (row >= B) return;

    const float* xp = x + (size_t)row * 19;
    float xr[19];
    #pragma unroll
    for (int i = 0; i < 19; ++i) xr[i] = xp[i];

    // h_j init: jcat (7,2) @ Wj.T + bj ; h_m init: obs (5) @ Wm.T + bm  (fp32, one-time)
    float hj[NJ][HID], hm[HID];
    #pragma unroll
    for (int t = 0; t < NJ; ++t)
        #pragma unroll
        for (int o = 0; o < HID; ++o)
            hj[t][o] = bj[o] + Wj[o*2+0]*xr[5+t] + Wj[o*2+1]*xr[12+t];
    #pragma unroll
    for (int o = 0; o < HID; ++o) {
        float a = bm[o];
        #pragma unroll
        for (int k = 0; k < 5; ++k) a += Wm[o*5+k]*xr[k];
        hm[o] = a;
    }

    for (int it = 0; it < 7; ++it) {
        // pack current states to half2
        half2_t hjp[NJ][2], hmp[2];
        #pragma unroll
        for (int t = 0; t < NJ; ++t) {
            hjp[t][0] = pk(hj[t][0], hj[t][1]);
            hjp[t][1] = pk(hj[t][2], hj[t][3]);
        }
        hmp[0] = pk(hm[0], hm[1]);
        hmp[1] = pk(hm[2], hm[3]);

        // ---- m-GRU: input hj[0], hidden hm ----
        float mrz[8];
        #pragma unroll
        for (int g = 0; g < 8; ++g) {
            float a = __uint_as_float(wu[136 + g]);
            a = fdot2f(h2(wu[72 + g*2 + 0]), hjp[0][0], a);
            a = fdot2f(h2(wu[72 + g*2 + 1]), hjp[0][1], a);
            a = fdot2f(h2(wu[96 + g*2 + 0]), hmp[0], a);
            a = fdot2f(h2(wu[96 + g*2 + 1]), hmp[1], a);
            mrz[g] = a;
        }
        float hmn[HID];
        #pragma unroll
        for (int i = 0; i < HID; ++i) {
            int gn = 8 + i;
            float gi = __uint_as_float(wu[144 + i]);
            gi = fdot2f(h2(wu[72 + gn*2 + 0]), hjp[0][0], gi);
            gi = fdot2f(h2(wu[72 + gn*2 + 1]), hjp[0][1], gi);
            float gh = __uint_as_float(wu[148 + i]);
            gh = fdot2f(h2(wu[96 + gn*2 + 0]), hmp[0], gh);
            gh = fdot2f(h2(wu[96 + gn*2 + 1]), hmp[1], gh);
            float r = __builtin_amdgcn_rcpf(1.0f + __builtin_amdgcn_exp2f(mrz[i]));
            float z = __builtin_amdgcn_rcpf(1.0f + __builtin_amdgcn_exp2f(mrz[4+i]));
            float v = gi + r * gh;
            float n = 1.0f - 2.0f * __builtin_amdgcn_rcpf(__builtin_amdgcn_exp2f(v) + 1.0f);
            hmn[i] = n + z * (hm[i] - n);
        }

        // ---- joint GRUs ----
        float hjn[NJ][HID];
        #pragma unroll
        for (int t = 0; t < NJ; ++t) {
            half2_t in0 = (t == 0) ? hmp[0] : hjp[t-1][0];
            half2_t in1 = (t == 0) ? hmp[1] : hjp[t-1][1];
            float rz[8];
            #pragma unroll
            for (int g = 0; g < 8; ++g) {
                float a = __uint_as_float(wu[120 + g]);
                a = fdot2f(h2(wu[g*4 + 0]), in0, a);
                a = fdot2f(h2(wu[g*4 + 1]), in1, a);
                if (t < 6) {
                    a = fdot2f(h2(wu[g*4 + 2]), hjp[t+1][0], a);
                    a = fdot2f(h2(wu[g*4 + 3]), hjp[t+1][1], a);
                }
                a = fdot2f(h2(wu[48 + g*2 + 0]), hjp[t][0], a);
                a = fdot2f(h2(wu[48 + g*2 + 1]), hjp[t][1], a);
                rz[g] = a;
            }
            #pragma unroll
            for (int i = 0; i < HID; ++i) {
                int gn = 8 + i;
                float gi = __uint_as_float(wu[128 + i]);
                gi = fdot2f(h2(wu[gn*4 + 0]), in0, gi);
                gi = fdot2f(h2(wu[gn*4 + 1]), in1, gi);
                if (t < 6) {
                    gi = fdot2f(h2(wu[gn*4 + 2]), hjp[t+1][0], gi);
                    gi = fdot2f(h2(wu[gn*4 + 3]), hjp[t+1][1], gi);
                }
                float gh = __uint_as_float(wu[132 + i]);
                gh = fdot2f(h2(wu[48 + gn*2 + 0]), hjp[t][0], gh);
                gh = fdot2f(h2(wu[48 + gn*2 + 1]), hjp[t][1], gh);
                float r = __builtin_amdgcn_rcpf(1.0f + __builtin_amdgcn_exp2f(rz[i]));
                float z = __builtin_amdgcn_rcpf(1.0f + __builtin_amdgcn_exp2f(rz[4+i]));
                float v = gi + r * gh;
                float n = 1.0f - 2.0f * __builtin_amdgcn_rcpf(__builtin_amdgcn_exp2f(v) + 1.0f);
                hjn[t][i] = n + z * (hj[t][i] - n);
            }
        }

        #pragma unroll
        for (int t = 0; t < NJ; ++t)
            #pragma unroll
            for (int i = 0; i < HID; ++i) hj[t][i] = hjn[t][i];
        #pragma unroll
        for (int i = 0; i < HID; ++i) hm[i] = hmn[i];
    }

    float* op = out + (size_t)row * 7;
    #pragma unroll
    for (int t = 0; t < NJ; ++t) {
        float a = bact[0];
        #pragma unroll
        for (int k = 0; k < HID; ++k) a += Wact[k] * hj[t][k];
        op[t] = a;
    }
}

extern "C" void kernel_launch(void* const* d_in, const int* in_sizes, int n_in,
                              void* d_out, int out_size, void* d_ws, size_t ws_size,
                              hipStream_t stream) {
    const float* x      = (const float*)d_in[0];
    const float* Wj     = (const float*)d_in[1];
    const float* bj     = (const float*)d_in[2];
    const float* Wm     = (const float*)d_in[3];
    const float* bm     = (const float*)d_in[4];
    const float* Wih_j  = (const float*)d_in[5];
    const float* Whh_j  = (const float*)d_in[6];
    const float* bih_j  = (const float*)d_in[7];
    const float* bhh_j  = (const float*)d_in[8];
    const float* Wih_m  = (const float*)d_in[9];
    const float* Whh_m  = (const float*)d_in[10];
    const float* bih_m  = (const float*)d_in[11];
    const float* bhh_m  = (const float*)d_in[12];
    const float* Wact   = (const float*)d_in[13];
    const float* bact   = (const float*)d_in[14];
    float* out = (float*)d_out;
    unsigned int* ws = (unsigned int*)d_ws;

    prep_kernel<<<1, 256, 0, stream>>>(Wih_j, Whh_j, bih_j, bhh_j,
                                       Wih_m, Whh_m, bih_m, bhh_m, ws);

    int B = in_sizes[0] / 19;
    const int block = 256;
    const int grid  = (B + block - 1) / block;
    aggreg_kernel<<<grid, block, 0, stream>>>(
        x, Wj, bj, Wm, bm, Wact, bact, ws, out, B);
}

// Round 4
// 526.340 us; speedup vs baseline: 2.1602x; 1.0006x over previous
//
#include <hip/hip_runtime.h>

typedef __attribute__((ext_vector_type(2))) _Float16 half2_t;

// ================= ws layout (u32 words) =================
// [u*88 + 0  .. +47]  rz gates:  8 gates x 6 half2 (k-pairs 0..11), scaled -log2e
// [u*88 + 48 .. +63]  gin:       4 gates x 4 half2 (k-pairs 0..7),  scaled 2log2e
// [u*88 + 64 .. +71]  ghn:       4 gates x 2 half2 (k-pairs 8..11), scaled 2log2e
// [u*88 + 72 .. +79]  bsum_rz:   8 f32  ((bih+bhh)*-log2e)
// [u*88 + 80 .. +83]  bin:       4 f32  (bih_n * 2log2e)
// [u*88 + 84 .. +87]  bhn:       4 f32  (bhh_n * 2log2e)
//   u=0: m-unit (Wih_m -> k0-3, zeros k4-7, Whh_m -> k8-11)
//   u=1..7: joint unit (Wih_j k0-7, Whh_j k8-11) -- identical, duplicated
// [704 + u*24 .. +23] init table: 4x5 f32 weights row-major + 4 f32 bias
//   u=0: Wm(4x5)+bm;  u>0: [Wj[o][0],Wj[o][1],0,0,0]x4 + bj
// [896..899] Wact f32 x4; [900] bact f32

__device__ __forceinline__ half2_t h2u(unsigned int u) {
    return __builtin_bit_cast(half2_t, u);
}
__device__ __forceinline__ half2_t pk(float a, float b) {
    return __builtin_bit_cast(half2_t, __builtin_amdgcn_cvt_pkrtz(a, b));
}
__device__ __forceinline__ float dot2(unsigned int w, half2_t xv, float c) {
#if __has_builtin(__builtin_amdgcn_fdot2)
    return __builtin_amdgcn_fdot2(h2u(w), xv, c, false);
#else
    half2_t a = h2u(w);
    return c + (float)a.x * (float)xv.x + (float)a.y * (float)xv.y;
#endif
}

__global__ __launch_bounds__(256) void prep_kernel(
    const float* __restrict__ Wj,    const float* __restrict__ bj,
    const float* __restrict__ Wm,    const float* __restrict__ bm,
    const float* __restrict__ Wih_j, const float* __restrict__ Whh_j,
    const float* __restrict__ bih_j, const float* __restrict__ bhh_j,
    const float* __restrict__ Wih_m, const float* __restrict__ Whh_m,
    const float* __restrict__ bih_m, const float* __restrict__ bhh_m,
    const float* __restrict__ Wact,  const float* __restrict__ bact,
    unsigned int* __restrict__ ws)
{
    int t = blockIdx.x * 256 + threadIdx.x;
    const float c1 = -1.44269504f;   // -log2(e) for r,z
    const float c2 = 2.88539008f;    // 2*log2(e) for n
    if (t < 704) {
        int u = t / 88, w = t % 88;
        auto W = [&](int g, int k) -> float {
            if (u == 0) return (k < 4) ? Wih_m[g*4 + k]
                                       : (k < 8 ? 0.0f : Whh_m[g*4 + (k-8)]);
            return (k < 8) ? Wih_j[g*8 + k] : Whh_j[g*4 + (k-8)];
        };
        if (w < 72) {
            int g, k; float s;
            if (w < 48)      { g = w/6;          k = (w%6)*2;          s = c1; }
            else if (w < 64) { g = 8 + (w-48)/4; k = ((w-48)%4)*2;     s = c2; }
            else             { g = 8 + (w-64)/2; k = 8 + ((w-64)%2)*2; s = c2; }
            ws[t] = __builtin_bit_cast(unsigned int, pk(W(g,k)*s, W(g,k+1)*s));
        } else if (w < 80) {
            int g = w - 72;
            float b = (u == 0) ? (bih_m[g] + bhh_m[g]) : (bih_j[g] + bhh_j[g]);
            ws[t] = __float_as_uint(b * c1);
        } else if (w < 84) {
            int i = w - 80;
            ws[t] = __float_as_uint(((u == 0) ? bih_m[8+i] : bih_j[8+i]) * c2);
        } else {
            int i = w - 84;
            ws[t] = __float_as_uint(((u == 0) ? bhh_m[8+i] : bhh_j[8+i]) * c2);
        }
    } else if (t < 896) {
        int j = t - 704; int u = j / 24, w = j % 24;
        float v;
        if (w < 20) { int o = w/5, k = w%5;
            v = (u == 0) ? Wm[o*5 + k] : (k < 2 ? Wj[o*2 + k] : 0.0f);
        } else { int o = w - 20; v = (u == 0) ? bm[o] : bj[o]; }
        ws[t] = __float_as_uint(v);
    } else if (t < 900) {
        ws[t] = __float_as_uint(Wact[t - 896]);
    } else if (t == 900) {
        ws[t] = __float_as_uint(bact[0]);
    }
}

__global__ __launch_bounds__(256) void aggreg_kernel(
    const float* __restrict__ x,
    const unsigned int* __restrict__ ws,
    float* __restrict__ out, int B)
{
    int tid = blockIdx.x * 256 + threadIdx.x;
    int row = tid >> 3;
    int u   = tid & 7;            // 0 = m-unit, 1..7 = joints 0..6
    if (row >= B) return;

    // ---- per-lane loop weights -> VGPRs (static indexing only) ----
    unsigned int wv[88];
    const uint4* wb = (const uint4*)(ws + (unsigned)u * 88u);
    #pragma unroll
    for (int i = 0; i < 22; ++i) {
        uint4 q = wb[i];
        wv[4*i+0] = q.x; wv[4*i+1] = q.y; wv[4*i+2] = q.z; wv[4*i+3] = q.w;
    }

    // ---- per-lane input gather ----
    const float* xr = x + (size_t)row * 19;
    float x0, x1, x2, x3, x4;
    if (u == 0) { x0 = xr[0]; x1 = xr[1]; x2 = xr[2]; x3 = xr[3]; x4 = xr[4]; }
    else        { x0 = xr[4 + u]; x1 = xr[11 + u]; x2 = 0.f; x3 = 0.f; x4 = 0.f; }

    // ---- init matvec (4x5 padded table) ----
    const float4* ib = (const float4*)(ws + 704 + (unsigned)u * 24u);
    float4 i0 = ib[0], i1 = ib[1], i2 = ib[2], i3 = ib[3], i4 = ib[4], i5 = ib[5];
    float h0 = i5.x + i0.x*x0 + i0.y*x1 + i0.z*x2 + i0.w*x3 + i1.x*x4;
    float h1 = i5.y + i1.y*x0 + i1.z*x1 + i1.w*x2 + i2.x*x3 + i2.y*x4;
    float h2 = i5.z + i2.z*x0 + i2.w*x1 + i3.x*x2 + i3.y*x3 + i3.z*x4;
    float h3 = i5.w + i3.w*x0 + i4.x*x1 + i4.y*x2 + i4.z*x3 + i4.w*x4;

    // ---- packed state + neighbor indices ----
    unsigned int P0 = __builtin_bit_cast(unsigned int, pk(h0, h1));
    unsigned int P1 = __builtin_bit_cast(unsigned int, pk(h2, h3));
    int lane = threadIdx.x & 63;
    int lsrc = (u == 0) ? lane + 1 : lane - 1;   // left: m-unit pulls joint0 (old hj0)
    int rsrc = lane + 1;                          // right neighbor (masked for u==7)
    bool rzero = (u == 7);                        // joint6 right = 0 (m's right weights are 0)

    for (int it = 0; it < 7; ++it) {
        // exchange OLD states (all reads before any update -> matches reference order)
        unsigned int L0 = (unsigned int)__shfl((int)P0, lsrc, 64);
        unsigned int L1 = (unsigned int)__shfl((int)P1, lsrc, 64);
        unsigned int R0 = (unsigned int)__shfl((int)P0, rsrc, 64);
        unsigned int R1 = (unsigned int)__shfl((int)P1, rsrc, 64);
        if (rzero) { R0 = 0u; R1 = 0u; }
        half2_t l0 = h2u(L0), l1 = h2u(L1), r0 = h2u(R0), r1 = h2u(R1);
        half2_t p0 = h2u(P0), p1 = h2u(P1);

        // rz gates (0..3 = r, 4..7 = z), args pre-scaled by -log2e
        float a[8];
        #pragma unroll
        for (int g = 0; g < 8; ++g) {
            float acc = __uint_as_float(wv[72 + g]);
            acc = dot2(wv[g*6 + 0], l0, acc);
            acc = dot2(wv[g*6 + 1], l1, acc);
            acc = dot2(wv[g*6 + 2], r0, acc);
            acc = dot2(wv[g*6 + 3], r1, acc);
            acc = dot2(wv[g*6 + 4], p0, acc);
            acc = dot2(wv[g*6 + 5], p1, acc);
            a[g] = acc;
        }
        // n-gate split accumulators, pre-scaled by 2log2e
        float gi[4], gh[4];
        #pragma unroll
        for (int i = 0; i < 4; ++i) {
            float acc = __uint_as_float(wv[80 + i]);
            acc = dot2(wv[48 + i*4 + 0], l0, acc);
            acc = dot2(wv[48 + i*4 + 1], l1, acc);
            acc = dot2(wv[48 + i*4 + 2], r0, acc);
            acc = dot2(wv[48 + i*4 + 3], r1, acc);
            gi[i] = acc;
            float acch = __uint_as_float(wv[84 + i]);
            acch = dot2(wv[64 + i*2 + 0], p0, acch);
            acch = dot2(wv[64 + i*2 + 1], p1, acch);
            gh[i] = acch;
        }
        // elementwise GRU update
        float hn[4]; float hcur[4] = {h0, h1, h2, h3};
        #pragma unroll
        for (int i = 0; i < 4; ++i) {
            float r = __builtin_amdgcn_rcpf(1.0f + __builtin_amdgcn_exp2f(a[i]));
            float z = __builtin_amdgcn_rcpf(1.0f + __builtin_amdgcn_exp2f(a[4+i]));
            float v = gi[i] + r * gh[i];
            float n = 1.0f - 2.0f * __builtin_amdgcn_rcpf(__builtin_amdgcn_exp2f(v) + 1.0f);
            hn[i] = n + z * (hcur[i] - n);
        }
        h0 = hn[0]; h1 = hn[1]; h2 = hn[2]; h3 = hn[3];
        P0 = __builtin_bit_cast(unsigned int, pk(h0, h1));
        P1 = __builtin_bit_cast(unsigned int, pk(h2, h3));
    }

    // ---- acts = hj @ Wact.T + bact (joint lanes only) ----
    if (u > 0) {
        const float* wa = (const float*)(ws + 896);
        float acc = wa[4] + wa[0]*h0 + wa[1]*h1 + wa[2]*h2 + wa[3]*h3;
        out[(size_t)row * 7 + (u - 1)] = acc;
    }
}

extern "C" void kernel_launch(void* const* d_in, const int* in_sizes, int n_in,
                              void* d_out, int out_size, void* d_ws, size_t ws_size,
                              hipStream_t stream) {
    const float* Wj     = (const float*)d_in[1];
    const float* bj     = (const float*)d_in[2];
    const float* Wm     = (const float*)d_in[3];
    const float* bm     = (const float*)d_in[4];
    const float* Wih_j  = (const float*)d_in[5];
    const float* Whh_j  = (const float*)d_in[6];
    const float* bih_j  = (const float*)d_in[7];
    const float* bhh_j  = (const float*)d_in[8];
    const float* Wih_m  = (const float*)d_in[9];
    const float* Whh_m  = (const float*)d_in[10];
    const float* bih_m  = (const float*)d_in[11];
    const float* bhh_m  = (const float*)d_in[12];
    const float* Wact   = (const float*)d_in[13];
    const float* bact   = (const float*)d_in[14];
    const float* x      = (const float*)d_in[0];
    float* out = (float*)d_out;
    unsigned int* ws = (unsigned int*)d_ws;

    prep_kernel<<<4, 256, 0, stream>>>(Wj, bj, Wm, bm,
                                       Wih_j, Whh_j, bih_j, bhh_j,
                                       Wih_m, Whh_m, bih_m, bhh_m,
                                       Wact, bact, ws);

    int B = in_sizes[0] / 19;                 // 2097152 rows
    long long threads = (long long)B * 8;
    int grid = (int)((threads + 255) / 256);  // exact multiple: full waves
    aggreg_kernel<<<grid, 256, 0, stream>>>(x, ws, out, B);
}